// Round 1
// baseline (148.071 us; speedup 1.0000x reference)
//
#include <hip/hip_runtime.h>

#define Bn 16
#define Tn 64
#define Cn 512
#define LDA 520   // bf16 elements per LDS row: 512 + 8 pad (16B-aligned, breaks bank aliasing)

typedef short s8v __attribute__((ext_vector_type(8)));   // 8 bf16 = one MFMA A/B fragment
typedef float f4v __attribute__((ext_vector_type(4)));   // MFMA accumulator

__device__ __forceinline__ unsigned short f2bf(float f){
  union { float f; unsigned int u; } c; c.f = f;
  return (unsigned short)((c.u + 0x7FFFu + ((c.u >> 16) & 1u)) >> 16);  // RNE
}
__device__ __forceinline__ float bf2f(unsigned short u){
  union { unsigned int u; float f; } c; c.u = ((unsigned int)u) << 16; return c.f;
}

// ---------------------------------------------------------------------------
// Swizzle W (512x512 f32, row-major [k][n]) into bf16 B-fragment order:
// frag index = (s*32 + t), s = kstep (K=32 each), t = ntile (N=16 each).
// Within a frag: lane l holds B[k = s*32 + (l>>4)*8 + j][n = t*16 + (l&15)], j=0..7.
// Storage: elem offset ((s*32+t)*64 + lane)*8  -> wave reads lane*16B contiguous 1KB.
// ---------------------------------------------------------------------------
__global__ void swz(const float* __restrict__ Wp, const float* __restrict__ Wx,
                    const float* __restrict__ Wi, unsigned short* __restrict__ dstall){
  int gid = blockIdx.x * 256 + threadIdx.x;        // 3 * 32768 threads
  int mat = gid >> 15;
  int rem = gid & 32767;
  int lane = rem & 63;
  int st   = rem >> 6;
  int t    = st & 31;
  int s    = st >> 5;
  int n  = t * 16 + (lane & 15);
  int k0 = s * 32 + ((lane >> 4) << 3);
  const float* W = (mat == 0) ? Wp : ((mat == 1) ? Wx : Wi);
  unsigned int p[4];
#pragma unroll
  for(int q = 0; q < 4; ++q){
    unsigned short lo = f2bf(W[(k0 + 2*q    ) * Cn + n]);
    unsigned short hi = f2bf(W[(k0 + 2*q + 1) * Cn + n]);
    p[q] = (unsigned int)lo | ((unsigned int)hi << 16);
  }
  uint4 o; o.x = p[0]; o.y = p[1]; o.z = p[2]; o.w = p[3];
  *reinterpret_cast<uint4*>(dstall + (size_t)mat * 262144 + (size_t)rem * 8) = o;
}

// ---------------------------------------------------------------------------
// Prep: values = x@W_proj + b_proj (stored bf16), xe = x@W_x + b_x (stored f32).
// One block per (b, mat): M=64 rows, N=512 (8 waves x 64 cols), K=512 MFMA.
// ---------------------------------------------------------------------------
__global__ void prep(const float* __restrict__ x, const float* __restrict__ bp,
                     const float* __restrict__ bx, const unsigned short* __restrict__ WswP,
                     const unsigned short* __restrict__ WswX,
                     float* __restrict__ xe, unsigned short* __restrict__ vbf){
  __shared__ unsigned short lA[Tn * LDA];
  const int b = blockIdx.x >> 1, mat = blockIdx.x & 1;
  const int tid = threadIdx.x;
  const int c0 = (tid & 127) * 4, jb = tid >> 7;
#pragma unroll
  for(int it = 0; it < 16; ++it){
    int j = jb + it * 4;
    f4v xv = *reinterpret_cast<const f4v*>(x + ((b * Tn + j) * Cn + c0));
    uint2 uu;
    uu.x = (unsigned int)f2bf(xv[0]) | ((unsigned int)f2bf(xv[1]) << 16);
    uu.y = (unsigned int)f2bf(xv[2]) | ((unsigned int)f2bf(xv[3]) << 16);
    *reinterpret_cast<uint2*>(&lA[j * LDA + c0]) = uu;
  }
  __syncthreads();
  const unsigned short* Wsw = mat ? WswX : WswP;
  const float* bias = mat ? bx : bp;
  const int lane = tid & 63, w = tid >> 6, quad = lane >> 4, ln = lane & 15;
  f4v acc[4][4];
#pragma unroll
  for(int mt = 0; mt < 4; ++mt)
#pragma unroll
    for(int nt = 0; nt < 4; ++nt){
      acc[mt][nt][0] = 0.f; acc[mt][nt][1] = 0.f; acc[mt][nt][2] = 0.f; acc[mt][nt][3] = 0.f;
    }
#pragma unroll 1
  for(int s = 0; s < 16; ++s){
    s8v af[4], bfv[4];
#pragma unroll
    for(int mt = 0; mt < 4; ++mt)
      af[mt] = *reinterpret_cast<const s8v*>(&lA[(mt * 16 + ln) * LDA + s * 32 + quad * 8]);
#pragma unroll
    for(int nt = 0; nt < 4; ++nt)
      bfv[nt] = *reinterpret_cast<const s8v*>(Wsw + (((s * 32) + (w * 4 + nt)) * 64 + lane) * 8);
#pragma unroll
    for(int mt = 0; mt < 4; ++mt)
#pragma unroll
      for(int nt = 0; nt < 4; ++nt)
        acc[mt][nt] = __builtin_amdgcn_mfma_f32_16x16x32_bf16(af[mt], bfv[nt], acc[mt][nt], 0, 0, 0);
  }
#pragma unroll
  for(int nt = 0; nt < 4; ++nt){
    int c = w * 64 + nt * 16 + ln;
    float bb = bias[c];
#pragma unroll
    for(int mt = 0; mt < 4; ++mt)
#pragma unroll
      for(int r = 0; r < 4; ++r){
        int j = mt * 16 + quad * 4 + r;
        float v = acc[mt][nt][r] + bb;
        int idx = (b * Tn + j) * Cn + c;
        if(mat == 0) vbf[idx] = f2bf(v);
        else         xe[idx]  = v;
      }
  }
}

// ---------------------------------------------------------------------------
// Fused main: one block per (b,i). Build A = relu(xe[b,j,:] + r0*Wt0 + r1*Wt1 + bt)
// in LDS (bf16), MFMA vs swizzled W_imp (direct global B-fragments, no barrier in
// K-loop), sigmoid+mask epilogue in regs, then rowsum (out1) + logsumexp (out0).
// ---------------------------------------------------------------------------
__global__ void fused(const float* __restrict__ x, const float* __restrict__ ts,
                      const float* __restrict__ am, const float* __restrict__ Wt,
                      const float* __restrict__ bt, const float* __restrict__ bimp,
                      const unsigned short* __restrict__ Wsw,
                      const float* __restrict__ xe, const unsigned short* __restrict__ vbf,
                      float* __restrict__ out0, float* __restrict__ out1){
  __shared__ unsigned short lA[Tn * LDA];
  __shared__ float tss[Tn], msk[Tn], rsum[Tn];
  const int b = blockIdx.x >> 6, i = blockIdx.x & 63;
  const int tid = threadIdx.x;
  if(tid < Tn){ tss[tid] = ts[b * Tn + tid]; msk[tid] = am[b * Tn + tid]; rsum[tid] = 0.f; }
  __syncthreads();
  const int c0 = (tid & 127) * 4, jb = tid >> 7;
  const float tsi = tss[i];
  f4v wt0 = *reinterpret_cast<const f4v*>(Wt + c0);
  f4v wt1 = *reinterpret_cast<const f4v*>(Wt + Cn + c0);
  f4v btv = *reinterpret_cast<const f4v*>(bt + c0);
#pragma unroll
  for(int it = 0; it < 16; ++it){
    int j = jb + it * 4;
    float d  = tsi - tss[j];
    float r0 = __logf(1.f + fmaxf(d, 0.f));
    float r1 = __logf(1.f + fmaxf(-d, 0.f));
    f4v xv = *reinterpret_cast<const f4v*>(xe + ((b * Tn + j) * Cn + c0));
    float h0 = fmaxf(xv[0] + r0 * wt0[0] + r1 * wt1[0] + btv[0], 0.f);
    float h1 = fmaxf(xv[1] + r0 * wt0[1] + r1 * wt1[1] + btv[1], 0.f);
    float h2 = fmaxf(xv[2] + r0 * wt0[2] + r1 * wt1[2] + btv[2], 0.f);
    float h3 = fmaxf(xv[3] + r0 * wt0[3] + r1 * wt1[3] + btv[3], 0.f);
    uint2 uu;
    uu.x = (unsigned int)f2bf(h0) | ((unsigned int)f2bf(h1) << 16);
    uu.y = (unsigned int)f2bf(h2) | ((unsigned int)f2bf(h3) << 16);
    *reinterpret_cast<uint2*>(&lA[j * LDA + c0]) = uu;
  }
  __syncthreads();

  const int lane = tid & 63, w = tid >> 6, quad = lane >> 4, ln = lane & 15;
  f4v acc[4][4];
#pragma unroll
  for(int mt = 0; mt < 4; ++mt)
#pragma unroll
    for(int nt = 0; nt < 4; ++nt){
      acc[mt][nt][0] = 0.f; acc[mt][nt][1] = 0.f; acc[mt][nt][2] = 0.f; acc[mt][nt][3] = 0.f;
    }
#pragma unroll 1
  for(int s = 0; s < 16; ++s){
    s8v af[4], bfv[4];
#pragma unroll
    for(int mt = 0; mt < 4; ++mt)
      af[mt] = *reinterpret_cast<const s8v*>(&lA[(mt * 16 + ln) * LDA + s * 32 + quad * 8]);
#pragma unroll
    for(int nt = 0; nt < 4; ++nt)
      bfv[nt] = *reinterpret_cast<const s8v*>(Wsw + (((s * 32) + (w * 4 + nt)) * 64 + lane) * 8);
#pragma unroll
    for(int mt = 0; mt < 4; ++mt)
#pragma unroll
      for(int nt = 0; nt < 4; ++nt)
        acc[mt][nt] = __builtin_amdgcn_mfma_f32_16x16x32_bf16(af[mt], bfv[nt], acc[mt][nt], 0, 0, 0);
  }

  // epilogue A: imp = mask[j] * sigmoid(logit + b_imp[c]), kept in acc regs
#pragma unroll
  for(int nt = 0; nt < 4; ++nt){
    int c = w * 64 + nt * 16 + ln;
    float bb = bimp[c];
#pragma unroll
    for(int mt = 0; mt < 4; ++mt)
#pragma unroll
      for(int r = 0; r < 4; ++r){
        int j = mt * 16 + quad * 4 + r;
        float z = acc[mt][nt][r] + bb;
        float im = msk[j] * __builtin_amdgcn_rcpf(1.f + __expf(-z));
        acc[mt][nt][r] = im;
      }
  }

  // out1 partial: sum over this wave's 64 c's for each j, via quad shuffle + LDS atomic
#pragma unroll
  for(int mt = 0; mt < 4; ++mt)
#pragma unroll
    for(int r = 0; r < 4; ++r){
      float p = acc[mt][0][r] + acc[mt][1][r] + acc[mt][2][r] + acc[mt][3][r];
      p += __shfl_xor(p, 1, 64);
      p += __shfl_xor(p, 2, 64);
      p += __shfl_xor(p, 4, 64);
      p += __shfl_xor(p, 8, 64);
      if(ln == 0) atomicAdd(&rsum[mt * 16 + quad * 4 + r], p);
    }
  __syncthreads();                     // all K-loop LDS reads + rsum adds done

  // reload lA with values (bf16) for the logsumexp
#pragma unroll
  for(int it = 0; it < 16; ++it){
    int j = jb + it * 4;
    *reinterpret_cast<uint2*>(&lA[j * LDA + c0]) =
        *reinterpret_cast<const uint2*>(vbf + (b * Tn + j) * Cn + c0);
  }
  __syncthreads();

  // out0: logsumexp over j of values[b,j,c] * imp[j,c]
#pragma unroll
  for(int nt = 0; nt < 4; ++nt){
    int c = w * 64 + nt * 16 + ln;
    float se = 0.f;
#pragma unroll
    for(int mt = 0; mt < 4; ++mt)
#pragma unroll
      for(int r = 0; r < 4; ++r){
        float v = bf2f(lA[(mt * 16 + quad * 4 + r) * LDA + c]);
        se += __expf(v * acc[mt][nt][r]);
      }
    se += __shfl_xor(se, 16, 64);
    se += __shfl_xor(se, 32, 64);
    if(quad == 0){
      int idx = (b * Tn + i) * Cn + c;
      out0[idx] = x[idx] + __logf(se);
    }
  }
  if(tid < Tn) out1[(b * Tn + i) * Tn + tid] = rsum[tid] * (1.f / 512.f);
}

extern "C" void kernel_launch(void* const* d_in, const int* in_sizes, int n_in,
                              void* d_out, int out_size, void* d_ws, size_t ws_size,
                              hipStream_t stream){
  const float* x    = (const float*)d_in[0];
  const float* ts   = (const float*)d_in[1];
  const float* am   = (const float*)d_in[2];
  const float* Wp   = (const float*)d_in[3];
  const float* bp   = (const float*)d_in[4];
  const float* Wx   = (const float*)d_in[5];
  const float* bx   = (const float*)d_in[6];
  const float* Wt   = (const float*)d_in[7];
  const float* bt   = (const float*)d_in[8];
  const float* Wi   = (const float*)d_in[9];
  const float* bimp = (const float*)d_in[10];
  float* out0 = (float*)d_out;
  float* out1 = out0 + Bn * Tn * Cn;

  char* ws = (char*)d_ws;
  unsigned short* Wsw = (unsigned short*)ws;                         // 3 x 512KB bf16 swizzled
  float* xe = (float*)(ws + 3 * 524288);                             // 2MB f32
  unsigned short* vbf = (unsigned short*)(ws + 3 * 524288 + 2097152); // 1MB bf16

  swz<<<384, 256, 0, stream>>>(Wp, Wx, Wi, Wsw);
  prep<<<32, 512, 0, stream>>>(x, bp, bx, Wsw, Wsw + 262144, xe, vbf);
  fused<<<1024, 512, 0, stream>>>(x, ts, am, Wt, bt, bimp, Wsw + 2 * 262144,
                                  xe, vbf, out0, out1);
}

// Round 2
// 135.118 us; speedup vs baseline: 1.0959x; 1.0959x over previous
//
#include <hip/hip_runtime.h>
#include <hip/hip_bf16.h>

#define Bn 16
#define Tn 64
#define Cn 512
#define LDA 520   // bf16 elems per LDS row: 512 + 8 pad

#define LOG2E 1.4426950408889634f
#define LN2   0.6931471805599453f

typedef short s8v __attribute__((ext_vector_type(8)));   // 8 bf16 = one MFMA frag
typedef float f4v __attribute__((ext_vector_type(4)));   // MFMA accumulator

__device__ __forceinline__ unsigned short f2bf(float f){
  union { float f; unsigned int u; } c; c.f = f;
  return (unsigned short)((c.u + 0x7FFFu + ((c.u >> 16) & 1u)) >> 16);  // RNE
}
__device__ __forceinline__ unsigned int pk2bf(float a, float b){
  __hip_bfloat162 t = __float22bfloat162_rn(make_float2(a, b));  // v_cvt_pk_bf16_f32
  union { __hip_bfloat162 h; unsigned int u; } c; c.h = t; return c.u;
}
__device__ __forceinline__ float bits2f(unsigned int u){
  union { unsigned int u; float f; } c; c.u = u; return c.f;
}

// ---------------------------------------------------------------------------
// swz: (a) W_proj/W_x/W_imp (512x512 f32 row-major [k][n]) -> bf16 B-fragment
// order (blocks 0..383); (b) R table: log1p(max(±(ts_i-ts_j),0)) per (b,i,j)
// (blocks 384..447).
// ---------------------------------------------------------------------------
__global__ void swz(const float* __restrict__ Wp, const float* __restrict__ Wx,
                    const float* __restrict__ Wi, const float* __restrict__ ts,
                    unsigned short* __restrict__ dstall, float* __restrict__ R){
  if(blockIdx.x < 384){
    int gid = blockIdx.x * 256 + threadIdx.x;        // 3 * 32768 threads
    int mat = gid >> 15;
    int rem = gid & 32767;
    int lane = rem & 63;
    int st   = rem >> 6;
    int t    = st & 31;
    int s    = st >> 5;
    int n  = t * 16 + (lane & 15);
    int k0 = s * 32 + ((lane >> 4) << 3);
    const float* W = (mat == 0) ? Wp : ((mat == 1) ? Wx : Wi);
    unsigned int p[4];
#pragma unroll
    for(int q = 0; q < 4; ++q)
      p[q] = pk2bf(W[(k0 + 2*q) * Cn + n], W[(k0 + 2*q + 1) * Cn + n]);
    uint4 o; o.x = p[0]; o.y = p[1]; o.z = p[2]; o.w = p[3];
    *reinterpret_cast<uint4*>(dstall + (size_t)mat * 262144 + (size_t)rem * 8) = o;
  } else {
    int gid2 = (blockIdx.x - 384) * 256 + threadIdx.x;   // 16384 threads, 4 pairs each
    float r[8];
#pragma unroll
    for(int q = 0; q < 4; ++q){
      int p = gid2 * 4 + q;                              // 65536 (b,i,j) triples
      int b = p >> 12, i = (p >> 6) & 63, j = p & 63;
      float d = ts[b * Tn + i] - ts[b * Tn + j];
      r[2*q]   = __logf(1.f + fmaxf(d, 0.f));
      r[2*q+1] = __logf(1.f + fmaxf(-d, 0.f));
    }
    float4* Rf4 = reinterpret_cast<float4*>(R);
    Rf4[gid2 * 2    ] = make_float4(r[0], r[1], r[2], r[3]);
    Rf4[gid2 * 2 + 1] = make_float4(r[4], r[5], r[6], r[7]);
  }
}

// ---------------------------------------------------------------------------
// prep: block = (b, mat, half); 256 threads (4 waves x 64 cols = N=256 half).
// mat=0: values = x@W_proj + b_proj, stored *log2e, bf16, in FRAGMENT ORDER
//        keyed (b, wg, eb, lane) so fused loads 8 coalesced dwordx4 / thread.
// mat=1: xe = x@W_x + b_x + b_t (f32 row-major; b_t folded in).
// ---------------------------------------------------------------------------
__global__ __launch_bounds__(256, 4)
void prep(const float* __restrict__ x, const float* __restrict__ bp,
          const float* __restrict__ bx, const float* __restrict__ bt,
          const unsigned short* __restrict__ WswP,
          const unsigned short* __restrict__ WswX,
          float* __restrict__ xe, unsigned short* __restrict__ vfrag){
  __shared__ unsigned short lA[Tn * LDA];
  const int b = blockIdx.x >> 2, mat = (blockIdx.x >> 1) & 1, half = blockIdx.x & 1;
  const int tid = threadIdx.x;
  const int c0 = (tid & 127) * 4, jb = tid >> 7;     // jb in {0,1}
#pragma unroll
  for(int it = 0; it < 32; ++it){
    int j = jb + it * 2;
    f4v xv = *reinterpret_cast<const f4v*>(x + ((b * Tn + j) * Cn + c0));
    uint2 uu; uu.x = pk2bf(xv[0], xv[1]); uu.y = pk2bf(xv[2], xv[3]);
    *reinterpret_cast<uint2*>(&lA[j * LDA + c0]) = uu;
  }
  __syncthreads();
  const unsigned short* Wsw = mat ? WswX : WswP;
  const int lane = tid & 63, w2 = tid >> 6, quad = lane >> 4, ln = lane & 15;
  const int wg = half * 4 + w2;                      // global 64-col chunk 0..7
  f4v acc[4][4];
#pragma unroll
  for(int mt = 0; mt < 4; ++mt)
#pragma unroll
    for(int nt = 0; nt < 4; ++nt){
      acc[mt][nt][0] = 0.f; acc[mt][nt][1] = 0.f; acc[mt][nt][2] = 0.f; acc[mt][nt][3] = 0.f;
    }
#pragma unroll 1
  for(int s = 0; s < 16; ++s){
    s8v af[4], bfv[4];
#pragma unroll
    for(int mt = 0; mt < 4; ++mt)
      af[mt] = *reinterpret_cast<const s8v*>(&lA[(mt * 16 + ln) * LDA + s * 32 + quad * 8]);
#pragma unroll
    for(int nt = 0; nt < 4; ++nt)
      bfv[nt] = *reinterpret_cast<const s8v*>(Wsw + (((s * 32) + (wg * 4 + nt)) * 64 + lane) * 8);
#pragma unroll
    for(int mt = 0; mt < 4; ++mt)
#pragma unroll
      for(int nt = 0; nt < 4; ++nt)
        acc[mt][nt] = __builtin_amdgcn_mfma_f32_16x16x32_bf16(af[mt], bfv[nt], acc[mt][nt], 0, 0, 0);
  }
  if(mat == 0){
    // fragment-order bf16 store, pre-scaled by log2e
#pragma unroll
    for(int eb = 0; eb < 8; ++eb){
      int mt = eb >> 1, ntb = (eb & 1) * 2;
      unsigned int wds[4];
#pragma unroll
      for(int h = 0; h < 2; ++h){
        int nt = ntb + h;
        float bb = bp[wg * 64 + nt * 16 + ln];
        float v0 = (acc[mt][nt][0] + bb) * LOG2E;
        float v1 = (acc[mt][nt][1] + bb) * LOG2E;
        float v2 = (acc[mt][nt][2] + bb) * LOG2E;
        float v3 = (acc[mt][nt][3] + bb) * LOG2E;
        wds[h*2]   = pk2bf(v0, v1);
        wds[h*2+1] = pk2bf(v2, v3);
      }
      uint4 o; o.x = wds[0]; o.y = wds[1]; o.z = wds[2]; o.w = wds[3];
      *reinterpret_cast<uint4*>(vfrag + ((size_t)((b * 8 + wg) * 8 + eb) * 64 + lane) * 8) = o;
    }
  } else {
#pragma unroll
    for(int nt = 0; nt < 4; ++nt){
      int c = wg * 64 + nt * 16 + ln;
      float bb = bx[c] + bt[c];                      // fold b_t into xe
#pragma unroll
      for(int mt = 0; mt < 4; ++mt)
#pragma unroll
        for(int r = 0; r < 4; ++r){
          int j = mt * 16 + quad * 4 + r;
          xe[(b * Tn + j) * Cn + c] = acc[mt][nt][r] + bb;
        }
    }
  }
}

// ---------------------------------------------------------------------------
// fused: one block per (b,i). A = relu(xe + r0*Wt0 + r1*Wt1) in LDS (bf16),
// MFMA vs W_imp fragments (global, no barrier in K-loop), sigmoid+mask in regs,
// rowsum -> out1, logsumexp with register-resident values -> out0.
// ---------------------------------------------------------------------------
__global__ __launch_bounds__(512, 4)
void fused(const float* __restrict__ x, const float* __restrict__ am,
           const float* __restrict__ Wt, const float* __restrict__ bimp,
           const unsigned short* __restrict__ Wsw, const float* __restrict__ R,
           const float* __restrict__ xe, const unsigned short* __restrict__ vfrag,
           float* __restrict__ out0, float* __restrict__ out1){
  __shared__ unsigned short lA[Tn * LDA];
  __shared__ float msk[Tn], rr0[Tn], rr1[Tn], rsum[Tn];
  const int b = blockIdx.x >> 6, i = blockIdx.x & 63;
  const int tid = threadIdx.x;
  if(tid < Tn){
    msk[tid] = am[b * Tn + tid];
    rsum[tid] = 0.f;
    float2 rv = reinterpret_cast<const float2*>(R)[(b * Tn + i) * Tn + tid];
    rr0[tid] = rv.x; rr1[tid] = rv.y;
  }
  __syncthreads();
  const int c0 = (tid & 127) * 4, jb = tid >> 7;
  f4v wt0 = *reinterpret_cast<const f4v*>(Wt + c0);
  f4v wt1 = *reinterpret_cast<const f4v*>(Wt + Cn + c0);
#pragma unroll
  for(int it = 0; it < 16; ++it){
    int j = jb + it * 4;
    float r0 = rr0[j], r1 = rr1[j];
    f4v xv = *reinterpret_cast<const f4v*>(xe + ((b * Tn + j) * Cn + c0));
    float h0 = fmaxf(fmaf(r1, wt1[0], fmaf(r0, wt0[0], xv[0])), 0.f);
    float h1 = fmaxf(fmaf(r1, wt1[1], fmaf(r0, wt0[1], xv[1])), 0.f);
    float h2 = fmaxf(fmaf(r1, wt1[2], fmaf(r0, wt0[2], xv[2])), 0.f);
    float h3 = fmaxf(fmaf(r1, wt1[3], fmaf(r0, wt0[3], xv[3])), 0.f);
    uint2 uu; uu.x = pk2bf(h0, h1); uu.y = pk2bf(h2, h3);
    *reinterpret_cast<uint2*>(&lA[j * LDA + c0]) = uu;
  }
  __syncthreads();

  const int lane = tid & 63, w = tid >> 6, quad = lane >> 4, ln = lane & 15;
  f4v acc[4][4];
#pragma unroll
  for(int mt = 0; mt < 4; ++mt)
#pragma unroll
    for(int nt = 0; nt < 4; ++nt){
      acc[mt][nt][0] = 0.f; acc[mt][nt][1] = 0.f; acc[mt][nt][2] = 0.f; acc[mt][nt][3] = 0.f;
    }
#pragma unroll 1
  for(int s = 0; s < 16; ++s){
    s8v af[4], bfv[4];
#pragma unroll
    for(int mt = 0; mt < 4; ++mt)
      af[mt] = *reinterpret_cast<const s8v*>(&lA[(mt * 16 + ln) * LDA + s * 32 + quad * 8]);
#pragma unroll
    for(int nt = 0; nt < 4; ++nt)
      bfv[nt] = *reinterpret_cast<const s8v*>(Wsw + (((s * 32) + (w * 4 + nt)) * 64 + lane) * 8);
#pragma unroll
    for(int mt = 0; mt < 4; ++mt)
#pragma unroll
      for(int nt = 0; nt < 4; ++nt)
        acc[mt][nt] = __builtin_amdgcn_mfma_f32_16x16x32_bf16(af[mt], bfv[nt], acc[mt][nt], 0, 0, 0);
  }

  // values (pre-scaled by log2e), fragment order: 8 coalesced 16B loads
  uint4 vv[8];
#pragma unroll
  for(int eb = 0; eb < 8; ++eb)
    vv[eb] = *reinterpret_cast<const uint4*>(vfrag + ((size_t)((b * 8 + w) * 8 + eb) * 64 + lane) * 8);

  // sigmoid + mask epilogue (in regs) fused with out1 rowsum
  float bb[4];
#pragma unroll
  for(int nt = 0; nt < 4; ++nt) bb[nt] = bimp[w * 64 + nt * 16 + ln];
#pragma unroll
  for(int mt = 0; mt < 4; ++mt)
#pragma unroll
    for(int r = 0; r < 4; ++r){
      float mk = msk[mt * 16 + quad * 4 + r];
      float p = 0.f;
#pragma unroll
      for(int nt = 0; nt < 4; ++nt){
        float z = acc[mt][nt][r] + bb[nt];
        float im = mk * __builtin_amdgcn_rcpf(1.f + __builtin_amdgcn_exp2f(z * -LOG2E));
        acc[mt][nt][r] = im;
        p += im;
      }
      p += __shfl_xor(p, 1, 64);
      p += __shfl_xor(p, 2, 64);
      p += __shfl_xor(p, 4, 64);
      p += __shfl_xor(p, 8, 64);
      if(ln == 0) atomicAdd(&rsum[mt * 16 + quad * 4 + r], p);
    }
  __syncthreads();
  if(tid < Tn) out1[(b * Tn + i) * Tn + tid] = rsum[tid] * (1.f / 512.f);

  // logsumexp over j: se = sum exp2(vl * imp), vl = values*log2e
  const unsigned int* vw = reinterpret_cast<const unsigned int*>(vv);
#pragma unroll
  for(int nt = 0; nt < 4; ++nt){
    float se = 0.f;
#pragma unroll
    for(int mt = 0; mt < 4; ++mt)
#pragma unroll
      for(int r = 0; r < 4; ++r){
        int e = mt * 16 + nt * 4 + r;
        unsigned int d = vw[e >> 1];
        float vl = bits2f((e & 1) ? (d & 0xffff0000u) : (d << 16));
        se += __builtin_amdgcn_exp2f(vl * acc[mt][nt][r]);
      }
    se += __shfl_xor(se, 16, 64);
    se += __shfl_xor(se, 32, 64);
    if(quad == 0){
      int idx = (b * Tn + i) * Cn + (w * 64 + nt * 16 + ln);
      out0[idx] = x[idx] + __builtin_amdgcn_logf(se) * LN2;
    }
  }
}

extern "C" void kernel_launch(void* const* d_in, const int* in_sizes, int n_in,
                              void* d_out, int out_size, void* d_ws, size_t ws_size,
                              hipStream_t stream){
  const float* x    = (const float*)d_in[0];
  const float* ts   = (const float*)d_in[1];
  const float* am   = (const float*)d_in[2];
  const float* Wp   = (const float*)d_in[3];
  const float* bp   = (const float*)d_in[4];
  const float* Wx   = (const float*)d_in[5];
  const float* bx   = (const float*)d_in[6];
  const float* Wt   = (const float*)d_in[7];
  const float* bt   = (const float*)d_in[8];
  const float* Wi   = (const float*)d_in[9];
  const float* bimp = (const float*)d_in[10];
  float* out0 = (float*)d_out;
  float* out1 = out0 + Bn * Tn * Cn;

  char* ws = (char*)d_ws;
  unsigned short* Wsw   = (unsigned short*)ws;                 // 3 x 512KB bf16 swizzled
  float*          xe    = (float*)(ws + 3 * 524288);           // 2MB f32 (x@Wx + bx + bt)
  unsigned short* vfrag = (unsigned short*)(ws + 3*524288 + 2097152); // 1MB bf16 frag-order
  float*          R     = (float*)(ws + 3*524288 + 2097152 + 1048576); // 512KB log1p table

  swz<<<448, 256, 0, stream>>>(Wp, Wx, Wi, ts, Wsw, R);
  prep<<<64, 256, 0, stream>>>(x, bp, bx, bt, Wsw, Wsw + 262144, xe, vfrag);
  fused<<<1024, 512, 0, stream>>>(x, am, Wt, bimp, Wsw + 2 * 262144, R,
                                  xe, vfrag, out0, out1);
}

// Round 3
// 126.310 us; speedup vs baseline: 1.1723x; 1.0697x over previous
//
#include <hip/hip_runtime.h>
#include <hip/hip_bf16.h>

#define Bn 16
#define Tn 64
#define Cn 512
#define LDA  520    // bf16 row stride in shorts (prep A tile)
#define LDA8 528    // fp8 row stride in bytes (fused A tile)

#define LOG2E 1.4426950408889634f
#define LN2   0.6931471805599453f
#define ASC 16.0f          // A (relu h) scale, folded into xe / Wt
#define WSC 256.0f         // W_imp scale (lifts out of e4m3 subnormals)
#define ZSC (1.0f/4096.0f) // 1/(ASC*WSC) unscale, folded into sigmoid

typedef short s8v __attribute__((ext_vector_type(8)));          // 8 bf16 frag
typedef float f4v __attribute__((ext_vector_type(4)));          // MFMA acc
typedef unsigned long ul2 __attribute__((ext_vector_type(2)));  // 2 fp8 frags

__device__ __forceinline__ unsigned int pk2bf(float a, float b){
  __hip_bfloat162 t = __float22bfloat162_rn(make_float2(a, b));
  union { __hip_bfloat162 h; unsigned int u; } c; c.h = t; return c.u;
}
__device__ __forceinline__ float bits2f(unsigned int u){
  union { unsigned int u; float f; } c; c.u = u; return c.f;
}

// ---------------------------------------------------------------------------
// swz:
//  blocks [0,256):   Wp/Wx f32 -> bf16 B-frag order (as before)
//  blocks [256,384): Wi f32 *256 -> fp8 e4m3, lane-contiguous frag layout:
//                    byte ((s*8 + w)*64 + lane)*32 + nt*8  (w=64-col chunk)
//  blocks [384,448): R table log1p(max(+/-(ts_i-ts_j),0))
// ---------------------------------------------------------------------------
__global__ void swz(const float* __restrict__ Wp, const float* __restrict__ Wx,
                    const float* __restrict__ Wi, const float* __restrict__ ts,
                    unsigned short* __restrict__ WswB, unsigned char* __restrict__ Wsw8,
                    float* __restrict__ R){
  int blk = blockIdx.x;
  if(blk < 256){
    int gid = blk * 256 + threadIdx.x;               // 65536 threads
    int mat = gid >> 15, rem = gid & 32767;
    int lane = rem & 63, st = rem >> 6, t = st & 31, s = st >> 5;
    int n  = t * 16 + (lane & 15);
    int k0 = s * 32 + ((lane >> 4) << 3);
    const float* W = mat ? Wx : Wp;
    unsigned int p[4];
#pragma unroll
    for(int q = 0; q < 4; ++q)
      p[q] = pk2bf(W[(k0 + 2*q) * Cn + n], W[(k0 + 2*q + 1) * Cn + n]);
    uint4 o; o.x = p[0]; o.y = p[1]; o.z = p[2]; o.w = p[3];
    *reinterpret_cast<uint4*>(WswB + (size_t)mat * 262144 + (size_t)rem * 8) = o;
  } else if(blk < 384){
    int rem = (blk - 256) * 256 + threadIdx.x;       // 32768 threads
    int nt = rem & 3, lane = (rem >> 2) & 63, w8 = (rem >> 8) & 7, s = rem >> 11;
    int n  = (w8 * 4 + nt) * 16 + (lane & 15);
    int k0 = s * 32 + ((lane >> 4) << 3);
    float v[8];
#pragma unroll
    for(int j = 0; j < 8; ++j) v[j] = Wi[(k0 + j) * Cn + n] * WSC;
    int d0 = __builtin_amdgcn_cvt_pk_fp8_f32(v[0], v[1], 0, false);
    d0     = __builtin_amdgcn_cvt_pk_fp8_f32(v[2], v[3], d0, true);
    int d1 = __builtin_amdgcn_cvt_pk_fp8_f32(v[4], v[5], 0, false);
    d1     = __builtin_amdgcn_cvt_pk_fp8_f32(v[6], v[7], d1, true);
    uint2 o; o.x = (unsigned int)d0; o.y = (unsigned int)d1;
    *reinterpret_cast<uint2*>(Wsw8 + (size_t)((s * 8 + w8) * 64 + lane) * 32 + nt * 8) = o;
  } else {
    int gid2 = (blk - 384) * 256 + threadIdx.x;      // 16384 threads, 4 pairs each
    float r[8];
#pragma unroll
    for(int q = 0; q < 4; ++q){
      int p = gid2 * 4 + q;
      int b = p >> 12, i = (p >> 6) & 63, j = p & 63;
      float d = ts[b * Tn + i] - ts[b * Tn + j];
      r[2*q]   = __logf(1.f + fmaxf(d, 0.f));
      r[2*q+1] = __logf(1.f + fmaxf(-d, 0.f));
    }
    float4* Rf4 = reinterpret_cast<float4*>(R);
    Rf4[gid2 * 2    ] = make_float4(r[0], r[1], r[2], r[3]);
    Rf4[gid2 * 2 + 1] = make_float4(r[4], r[5], r[6], r[7]);
  }
}

// ---------------------------------------------------------------------------
// prep: 256 blocks = (b, mat, oct). 256 threads, 4 waves; wave = 1 n-tile (16
// cols), full M=64, K=512, pipelined (B global + A LDS prefetch).
// mat=0: values -> vfrag bf16 *log2e (fused's C-frag order)
// mat=1: xe = (x@Wx + bx + bt) * ASC  (f32 row-major)
// ---------------------------------------------------------------------------
__global__ __launch_bounds__(256)
void prep(const float* __restrict__ x, const float* __restrict__ bp,
          const float* __restrict__ bx, const float* __restrict__ bt,
          const unsigned short* __restrict__ WswB,
          float* __restrict__ xe, unsigned short* __restrict__ vfrag){
  __shared__ unsigned short lA[Tn * LDA];
  const int blk = blockIdx.x;
  const int b = blk >> 4, mat = (blk >> 3) & 1, oct = blk & 7;
  const int tid = threadIdx.x;
  const int lane = tid & 63, w2 = tid >> 6, quad = lane >> 4, ln = lane & 15;
  const int t = oct * 4 + w2;

  // B-frag pointer (bf16 layout): s8v index (s*32 + t)*64 + lane
  const s8v* Bp = reinterpret_cast<const s8v*>(WswB + (size_t)mat * 262144) + (t * 64 + lane);
  s8v bcur = Bp[0];                                  // s=0 prefetch, overlaps staging

  const int c0 = (tid & 127) * 4, jb = tid >> 7;
#pragma unroll
  for(int it = 0; it < 32; ++it){
    int j = jb + it * 2;
    f4v xv = *reinterpret_cast<const f4v*>(x + ((b * Tn + j) * Cn + c0));
    uint2 uu; uu.x = pk2bf(xv[0], xv[1]); uu.y = pk2bf(xv[2], xv[3]);
    *reinterpret_cast<uint2*>(&lA[j * LDA + c0]) = uu;
  }
  __syncthreads();

  s8v a[4], an[4];
#pragma unroll
  for(int mt = 0; mt < 4; ++mt)
    a[mt] = *reinterpret_cast<const s8v*>(&lA[(mt * 16 + ln) * LDA + quad * 8]);
  f4v acc[4];
#pragma unroll
  for(int mt = 0; mt < 4; ++mt){ acc[mt][0]=0.f; acc[mt][1]=0.f; acc[mt][2]=0.f; acc[mt][3]=0.f; }

#pragma unroll 2
  for(int s = 0; s < 16; ++s){
    int sn = (s + 1) & 15;
    s8v bn = Bp[sn * 2048];
#pragma unroll
    for(int mt = 0; mt < 4; ++mt)
      an[mt] = *reinterpret_cast<const s8v*>(&lA[(mt * 16 + ln) * LDA + sn * 32 + quad * 8]);
#pragma unroll
    for(int mt = 0; mt < 4; ++mt)
      acc[mt] = __builtin_amdgcn_mfma_f32_16x16x32_bf16(a[mt], bcur, acc[mt], 0, 0, 0);
#pragma unroll
    for(int mt = 0; mt < 4; ++mt) a[mt] = an[mt];
    bcur = bn;
  }

  const int c = t * 16 + ln;
  if(mat == 0){
    float bb = bp[c];
    const int eb_h = w2 & 1;
#pragma unroll
    for(int mt = 0; mt < 4; ++mt){
      float v0 = (acc[mt][0] + bb) * LOG2E;
      float v1 = (acc[mt][1] + bb) * LOG2E;
      float v2 = (acc[mt][2] + bb) * LOG2E;
      float v3 = (acc[mt][3] + bb) * LOG2E;
      uint2 o; o.x = pk2bf(v0, v1); o.y = pk2bf(v2, v3);
      int eb = mt * 2 + (w2 >> 1);
      *reinterpret_cast<uint2*>(vfrag + ((size_t)((b * 8 + oct) * 8 + eb) * 64 + lane) * 8 + eb_h * 4) = o;
    }
  } else {
    float bb = bx[c] + bt[c];
#pragma unroll
    for(int mt = 0; mt < 4; ++mt)
#pragma unroll
      for(int r = 0; r < 4; ++r){
        int j = mt * 16 + quad * 4 + r;
        xe[(b * Tn + j) * Cn + c] = (acc[mt][r] + bb) * ASC;
      }
  }
}

// ---------------------------------------------------------------------------
// fused: one block per (b,i). A = relu(xe + r0*wt0 + r1*wt1) (pre-scaled x16)
// -> fp8 LDS tile; K-loop: fp8 MFMA vs W_imp (x256) with full double-buffer
// prefetch (B: 2 coalesced dwordx4/s from L2; A: 4 ds_read_b64/s). Sigmoid
// (unscale 1/4096) + mask in regs, rowsum -> out1, logsumexp -> out0.
// ---------------------------------------------------------------------------
__global__ __launch_bounds__(512, 4)
void fused(const float* __restrict__ x, const float* __restrict__ am,
           const float* __restrict__ Wt, const float* __restrict__ bimp,
           const unsigned char* __restrict__ Wsw8, const float* __restrict__ R,
           const float* __restrict__ xe, const unsigned short* __restrict__ vfrag,
           float* __restrict__ out0, float* __restrict__ out1){
  __shared__ unsigned char lA8[Tn * LDA8];
  __shared__ float msk[Tn], rr0[Tn], rr1[Tn], rsum[Tn];
  const int b = blockIdx.x >> 6, i = blockIdx.x & 63;
  const int tid = threadIdx.x;
  if(tid < Tn){
    msk[tid] = am[b * Tn + tid];
    rsum[tid] = 0.f;
    float2 rv = reinterpret_cast<const float2*>(R)[(b * Tn + i) * Tn + tid];
    rr0[tid] = rv.x; rr1[tid] = rv.y;
  }
  __syncthreads();

  const int lane = tid & 63, w = tid >> 6, quad = lane >> 4, ln = lane & 15;
  // B s=0 prefetch (independent of LDS) — issued before the A-build
  const ul2* Bv = reinterpret_cast<const ul2*>(Wsw8);
  const int off = (w * 64 + lane) * 2;
  ul2 b01 = Bv[off], b23 = Bv[off + 1];

  const int c0 = (tid & 127) * 4, jb = tid >> 7;
  f4v wt0 = *reinterpret_cast<const f4v*>(Wt + c0);
  f4v wt1 = *reinterpret_cast<const f4v*>(Wt + Cn + c0);
  wt0[0]*=ASC; wt0[1]*=ASC; wt0[2]*=ASC; wt0[3]*=ASC;   // xe already x16
  wt1[0]*=ASC; wt1[1]*=ASC; wt1[2]*=ASC; wt1[3]*=ASC;
#pragma unroll
  for(int it = 0; it < 16; ++it){
    int j = jb + it * 4;
    float r0 = rr0[j], r1 = rr1[j];
    f4v xv = *reinterpret_cast<const f4v*>(xe + ((b * Tn + j) * Cn + c0));
    float h0 = fmaxf(fmaf(r1, wt1[0], fmaf(r0, wt0[0], xv[0])), 0.f);
    float h1 = fmaxf(fmaf(r1, wt1[1], fmaf(r0, wt0[1], xv[1])), 0.f);
    float h2 = fmaxf(fmaf(r1, wt1[2], fmaf(r0, wt0[2], xv[2])), 0.f);
    float h3 = fmaxf(fmaf(r1, wt1[3], fmaf(r0, wt0[3], xv[3])), 0.f);
    int d = __builtin_amdgcn_cvt_pk_fp8_f32(h0, h1, 0, false);
    d     = __builtin_amdgcn_cvt_pk_fp8_f32(h2, h3, d, true);
    *reinterpret_cast<int*>(lA8 + j * LDA8 + c0) = d;
  }
  __syncthreads();

  unsigned long a[4], an[4];
#pragma unroll
  for(int mt = 0; mt < 4; ++mt)
    a[mt] = *reinterpret_cast<const unsigned long*>(lA8 + (mt * 16 + ln) * LDA8 + quad * 8);
  f4v acc[4][4];
#pragma unroll
  for(int mt = 0; mt < 4; ++mt)
#pragma unroll
    for(int nt = 0; nt < 4; ++nt){
      acc[mt][nt][0]=0.f; acc[mt][nt][1]=0.f; acc[mt][nt][2]=0.f; acc[mt][nt][3]=0.f;
    }

#pragma unroll 2
  for(int s = 0; s < 16; ++s){
    int sn = (s + 1) & 15;
    ul2 nb01 = Bv[sn * 1024 + off];
    ul2 nb23 = Bv[sn * 1024 + off + 1];
#pragma unroll
    for(int mt = 0; mt < 4; ++mt)
      an[mt] = *reinterpret_cast<const unsigned long*>(lA8 + (mt * 16 + ln) * LDA8 + sn * 32 + quad * 8);
    long bf0 = (long)b01.x, bf1 = (long)b01.y, bf2 = (long)b23.x, bf3 = (long)b23.y;
#pragma unroll
    for(int mt = 0; mt < 4; ++mt){
      acc[mt][0] = __builtin_amdgcn_mfma_f32_16x16x32_fp8_fp8((long)a[mt], bf0, acc[mt][0], 0, 0, 0);
      acc[mt][1] = __builtin_amdgcn_mfma_f32_16x16x32_fp8_fp8((long)a[mt], bf1, acc[mt][1], 0, 0, 0);
      acc[mt][2] = __builtin_amdgcn_mfma_f32_16x16x32_fp8_fp8((long)a[mt], bf2, acc[mt][2], 0, 0, 0);
      acc[mt][3] = __builtin_amdgcn_mfma_f32_16x16x32_fp8_fp8((long)a[mt], bf3, acc[mt][3], 0, 0, 0);
    }
#pragma unroll
    for(int mt = 0; mt < 4; ++mt) a[mt] = an[mt];
    b01 = nb01; b23 = nb23;
  }

  // values (bf16, pre-scaled by log2e), fragment order: 8 coalesced 16B loads
  uint4 vv[8];
#pragma unroll
  for(int eb = 0; eb < 8; ++eb)
    vv[eb] = *reinterpret_cast<const uint4*>(vfrag + ((size_t)((b * 8 + w) * 8 + eb) * 64 + lane) * 8);

  // sigmoid (with 1/4096 unscale) + mask, fused with out1 rowsum
  float bb[4];
#pragma unroll
  for(int nt = 0; nt < 4; ++nt) bb[nt] = bimp[w * 64 + nt * 16 + ln];
#pragma unroll
  for(int mt = 0; mt < 4; ++mt)
#pragma unroll
    for(int r = 0; r < 4; ++r){
      float mk = msk[mt * 16 + quad * 4 + r];
      float p = 0.f;
#pragma unroll
      for(int nt = 0; nt < 4; ++nt){
        float z = fmaf(acc[mt][nt][r], ZSC, bb[nt]);
        float im = mk * __builtin_amdgcn_rcpf(1.f + __builtin_amdgcn_exp2f(z * -LOG2E));
        acc[mt][nt][r] = im;
        p += im;
      }
      p += __shfl_xor(p, 1, 64);
      p += __shfl_xor(p, 2, 64);
      p += __shfl_xor(p, 4, 64);
      p += __shfl_xor(p, 8, 64);
      if(ln == 0) atomicAdd(&rsum[mt * 16 + quad * 4 + r], p);
    }
  __syncthreads();
  if(tid < Tn) out1[(b * Tn + i) * Tn + tid] = rsum[tid] * (1.f / 512.f);

  // logsumexp over j: se = sum exp2(vl * imp), vl = values*log2e
  const unsigned int* vw = reinterpret_cast<const unsigned int*>(vv);
#pragma unroll
  for(int nt = 0; nt < 4; ++nt){
    float se = 0.f;
#pragma unroll
    for(int mt = 0; mt < 4; ++mt)
#pragma unroll
      for(int r = 0; r < 4; ++r){
        int e = mt * 16 + nt * 4 + r;
        unsigned int d = vw[e >> 1];
        float vl = bits2f((e & 1) ? (d & 0xffff0000u) : (d << 16));
        se += __builtin_amdgcn_exp2f(vl * acc[mt][nt][r]);
      }
    se += __shfl_xor(se, 16, 64);
    se += __shfl_xor(se, 32, 64);
    if(quad == 0){
      int idx = (b * Tn + i) * Cn + (w * 64 + nt * 16 + ln);
      out0[idx] = x[idx] + __builtin_amdgcn_logf(se) * LN2;
    }
  }
}

extern "C" void kernel_launch(void* const* d_in, const int* in_sizes, int n_in,
                              void* d_out, int out_size, void* d_ws, size_t ws_size,
                              hipStream_t stream){
  const float* x    = (const float*)d_in[0];
  const float* ts   = (const float*)d_in[1];
  const float* am   = (const float*)d_in[2];
  const float* Wp   = (const float*)d_in[3];
  const float* bp   = (const float*)d_in[4];
  const float* Wx   = (const float*)d_in[5];
  const float* bx   = (const float*)d_in[6];
  const float* Wt   = (const float*)d_in[7];
  const float* bt   = (const float*)d_in[8];
  const float* Wi   = (const float*)d_in[9];
  const float* bimp = (const float*)d_in[10];
  float* out0 = (float*)d_out;
  float* out1 = out0 + Bn * Tn * Cn;

  char* ws = (char*)d_ws;
  unsigned short* WswB  = (unsigned short*)ws;                  // 1MB: Wp,Wx bf16 frags
  unsigned char*  Wsw8  = (unsigned char*)(ws + 1048576);       // 256KB: Wi fp8 frags
  float*          xe    = (float*)(ws + 1310720);               // 2MB f32 (scaled x16)
  unsigned short* vfrag = (unsigned short*)(ws + 3407872);      // 1MB bf16 frag-order
  float*          R     = (float*)(ws + 4456448);               // 512KB log1p table

  swz<<<448, 256, 0, stream>>>(Wp, Wx, Wi, ts, WswB, Wsw8, R);
  prep<<<256, 256, 0, stream>>>(x, bp, bx, bt, WswB, xe, vfrag);
  fused<<<1024, 512, 0, stream>>>(x, am, Wt, bimp, Wsw8, R, xe, vfrag, out0, out1);
}

// Round 4
// 123.218 us; speedup vs baseline: 1.2017x; 1.0251x over previous
//
#include <hip/hip_runtime.h>
#include <hip/hip_bf16.h>

#define Bn 16
#define Tn 64
#define Cn 512
#define LDA  520    // bf16 row stride in shorts (pre A tile)
#define LDA8 528    // fp8 row stride in bytes (fused A tile)

#define LOG2E 1.4426950408889634f
#define LN2   0.6931471805599453f
#define ASC 16.0f          // A (relu h) scale, folded into xe / Wt
#define WSC 256.0f         // W_imp scale (lifts out of e4m3 subnormals)
#define ZSC (1.0f/4096.0f) // 1/(ASC*WSC) unscale, folded into sigmoid

typedef short s8v __attribute__((ext_vector_type(8)));          // 8 bf16 frag
typedef float f4v __attribute__((ext_vector_type(4)));          // MFMA acc
typedef unsigned long ul2 __attribute__((ext_vector_type(2)));  // 2 fp8 frags

__device__ __forceinline__ unsigned int pk2bf(float a, float b){
  __hip_bfloat162 t = __float22bfloat162_rn(make_float2(a, b));
  union { __hip_bfloat162 h; unsigned int u; } c; c.h = t; return c.u;
}
__device__ __forceinline__ float bits2f(unsigned int u){
  union { unsigned int u; float f; } c; c.u = u; return c.f;
}
__device__ __forceinline__ s8v pack_bf8(const float* v){
  union { uint4 u; s8v s; } c;
  c.u.x = pk2bf(v[0], v[1]); c.u.y = pk2bf(v[2], v[3]);
  c.u.z = pk2bf(v[4], v[5]); c.u.w = pk2bf(v[6], v[7]);
  return c.s;
}

// ---------------------------------------------------------------------------
// pre: single dispatch, 448 blocks x 256 thr.
//  [0,64):    R table log1p(max(+/-(ts_i-ts_j),0))           -> R
//  [64,192):  Wi f32 *256 -> fp8 e4m3, lane-contig frag order -> Wsw8
//  [192,448): GEMM blocks (b, mat, oct): self-swizzling B from global W.
//     mat=0: values=x@Wp+bp -> vfrag bf16 *log2e (fused C-frag order)
//     mat=1: xe=(x@Wx+bx+bt)*ASC (f32 row-major)
// ---------------------------------------------------------------------------
__global__ __launch_bounds__(256)
void pre(const float* __restrict__ x, const float* __restrict__ ts,
         const float* __restrict__ Wp, const float* __restrict__ bp,
         const float* __restrict__ Wx, const float* __restrict__ bx,
         const float* __restrict__ bt, const float* __restrict__ Wi,
         float* __restrict__ xe, unsigned short* __restrict__ vfrag,
         unsigned char* __restrict__ Wsw8, float* __restrict__ R){
  __shared__ unsigned short lA[Tn * LDA];
  const int blk = blockIdx.x;
  const int tid = threadIdx.x;
  if(blk < 64){
    int gid2 = blk * 256 + tid;                      // 16384 threads, 4 pairs each
    float r[8];
#pragma unroll
    for(int q = 0; q < 4; ++q){
      int p = gid2 * 4 + q;
      int b = p >> 12, i = (p >> 6) & 63, j = p & 63;
      float d = ts[b * Tn + i] - ts[b * Tn + j];
      r[2*q]   = __logf(1.f + fmaxf(d, 0.f));
      r[2*q+1] = __logf(1.f + fmaxf(-d, 0.f));
    }
    float4* Rf4 = reinterpret_cast<float4*>(R);
    Rf4[gid2 * 2    ] = make_float4(r[0], r[1], r[2], r[3]);
    Rf4[gid2 * 2 + 1] = make_float4(r[4], r[5], r[6], r[7]);
    return;
  }
  if(blk < 192){
    int rem = (blk - 64) * 256 + tid;                // 32768 threads
    int nt = rem & 3, lane = (rem >> 2) & 63, w8 = (rem >> 8) & 7, s = rem >> 11;
    int n  = (w8 * 4 + nt) * 16 + (lane & 15);
    int k0 = s * 32 + ((lane >> 4) << 3);
    float v[8];
#pragma unroll
    for(int j = 0; j < 8; ++j) v[j] = Wi[(k0 + j) * Cn + n] * WSC;
    int d0 = __builtin_amdgcn_cvt_pk_fp8_f32(v[0], v[1], 0, false);
    d0     = __builtin_amdgcn_cvt_pk_fp8_f32(v[2], v[3], d0, true);
    int d1 = __builtin_amdgcn_cvt_pk_fp8_f32(v[4], v[5], 0, false);
    d1     = __builtin_amdgcn_cvt_pk_fp8_f32(v[6], v[7], d1, true);
    uint2 o; o.x = (unsigned int)d0; o.y = (unsigned int)d1;
    *reinterpret_cast<uint2*>(Wsw8 + (size_t)((s * 8 + w8) * 64 + lane) * 32 + nt * 8) = o;
    return;
  }
  // ---- GEMM blocks ----
  const int idx = blk - 192;
  const int b = idx >> 4, mat = (idx >> 3) & 1, oct = idx & 7;
  const int lane = tid & 63, w2 = tid >> 6, quad = lane >> 4, ln = lane & 15;
  const int t = oct * 4 + w2;
  const float* Wg = mat ? Wx : Wp;
  // lane's B base: rows quad*8 .. +7, col t*16+ln; s-step advances 32 rows
  const float* wb = Wg + (size_t)(quad * 8) * Cn + t * 16 + ln;

  const int c0 = (tid & 127) * 4, jb = tid >> 7;     // jb in {0,1}
#pragma unroll
  for(int it = 0; it < 32; ++it){
    int j = jb + it * 2;
    f4v xv = *reinterpret_cast<const f4v*>(x + ((b * Tn + j) * Cn + c0));
    uint2 uu; uu.x = pk2bf(xv[0], xv[1]); uu.y = pk2bf(xv[2], xv[3]);
    *reinterpret_cast<uint2*>(&lA[j * LDA + c0]) = uu;
  }
  // s=0 B load (global, independent of LDS)
  float wv[8];
#pragma unroll
  for(int j = 0; j < 8; ++j) wv[j] = wb[j * Cn];
  __syncthreads();

  s8v a[4], an[4];
#pragma unroll
  for(int mt = 0; mt < 4; ++mt)
    a[mt] = *reinterpret_cast<const s8v*>(&lA[(mt * 16 + ln) * LDA + quad * 8]);
  f4v acc[4];
#pragma unroll
  for(int mt = 0; mt < 4; ++mt){ acc[mt][0]=0.f; acc[mt][1]=0.f; acc[mt][2]=0.f; acc[mt][3]=0.f; }
  s8v bcur = pack_bf8(wv);

#pragma unroll 2
  for(int s = 0; s < 16; ++s){
    int sn = (s + 1) & 15;
    float wn[8];
#pragma unroll
    for(int j = 0; j < 8; ++j) wn[j] = wb[(size_t)sn * 32 * Cn + j * Cn];
#pragma unroll
    for(int mt = 0; mt < 4; ++mt)
      an[mt] = *reinterpret_cast<const s8v*>(&lA[(mt * 16 + ln) * LDA + sn * 32 + quad * 8]);
#pragma unroll
    for(int mt = 0; mt < 4; ++mt)
      acc[mt] = __builtin_amdgcn_mfma_f32_16x16x32_bf16(a[mt], bcur, acc[mt], 0, 0, 0);
#pragma unroll
    for(int mt = 0; mt < 4; ++mt) a[mt] = an[mt];
    bcur = pack_bf8(wn);
  }

  const int c = t * 16 + ln;
  if(mat == 0){
    float bb = bp[c];
    const int eb_h = w2 & 1;
#pragma unroll
    for(int mt = 0; mt < 4; ++mt){
      float v0 = (acc[mt][0] + bb) * LOG2E;
      float v1 = (acc[mt][1] + bb) * LOG2E;
      float v2 = (acc[mt][2] + bb) * LOG2E;
      float v3 = (acc[mt][3] + bb) * LOG2E;
      uint2 o; o.x = pk2bf(v0, v1); o.y = pk2bf(v2, v3);
      int eb = mt * 2 + (w2 >> 1);
      *reinterpret_cast<uint2*>(vfrag + ((size_t)((b * 8 + oct) * 8 + eb) * 64 + lane) * 8 + eb_h * 4) = o;
    }
  } else {
    float bb = bx[c] + bt[c];
#pragma unroll
    for(int mt = 0; mt < 4; ++mt)
#pragma unroll
      for(int r = 0; r < 4; ++r){
        int j = mt * 16 + quad * 4 + r;
        xe[(b * Tn + j) * Cn + c] = (acc[mt][r] + bb) * ASC;
      }
  }
}

// ---------------------------------------------------------------------------
// fused: one block per (b,i). xe loads + first B-frags hoisted above barrier;
// B prefetch depth 2; K-loop phase rotated by 8 per block parity to desync
// the two resident blocks. fp8 MFMA vs W_imp; sigmoid+mask in regs; rowsum
// -> out1; logsumexp -> out0.
// ---------------------------------------------------------------------------
__global__ __launch_bounds__(512, 4)
void fused(const float* __restrict__ x, const float* __restrict__ am,
           const float* __restrict__ Wt, const float* __restrict__ bimp,
           const unsigned char* __restrict__ Wsw8, const float* __restrict__ R,
           const float* __restrict__ xe, const unsigned short* __restrict__ vfrag,
           float* __restrict__ out0, float* __restrict__ out1){
  __shared__ unsigned char lA8[Tn * LDA8];
  __shared__ float msk[Tn], rr0[Tn], rr1[Tn], rsum[Tn];
  const int b = blockIdx.x >> 6, i = blockIdx.x & 63;
  const int tid = threadIdx.x;
  const int lane = tid & 63, w = tid >> 6, quad = lane >> 4, ln = lane & 15;
  const int ph = (blockIdx.x & 1) << 3;              // K-loop phase 0 / 8

  // small staging loads first (their waitcnt covers only these)
  float mv = 0.f; float2 rv = make_float2(0.f, 0.f);
  if(tid < Tn){
    mv = am[b * Tn + tid];
    rv = reinterpret_cast<const float2*>(R)[(b * Tn + i) * Tn + tid];
  }

  // hoisted xe loads: all 16 rows' worth for this thread, in flight across barrier
  const int c0 = (tid & 127) * 4, jb = tid >> 7;
  f4v xv[16];
#pragma unroll
  for(int it = 0; it < 16; ++it)
    xv[it] = *reinterpret_cast<const f4v*>(xe + ((b * Tn + (jb + it * 4)) * Cn + c0));

  // hoisted B prefetch for phases ph, ph+1
  const ul2* Bv = reinterpret_cast<const ul2*>(Wsw8);
  const int off = (w * 64 + lane) * 2;
  ul2 bA[2], bB[2];
  bA[0] = Bv[ph * 1024 + off];       bB[0] = Bv[ph * 1024 + off + 1];
  bA[1] = Bv[(ph + 1) * 1024 + off]; bB[1] = Bv[(ph + 1) * 1024 + off + 1];

  if(tid < Tn){ msk[tid] = mv; rr0[tid] = rv.x; rr1[tid] = rv.y; rsum[tid] = 0.f; }
  __syncthreads();

  f4v wt0 = *reinterpret_cast<const f4v*>(Wt + c0);
  f4v wt1 = *reinterpret_cast<const f4v*>(Wt + Cn + c0);
  wt0[0]*=ASC; wt0[1]*=ASC; wt0[2]*=ASC; wt0[3]*=ASC;   // xe already x16
  wt1[0]*=ASC; wt1[1]*=ASC; wt1[2]*=ASC; wt1[3]*=ASC;
#pragma unroll
  for(int it = 0; it < 16; ++it){
    int j = jb + it * 4;
    float r0 = rr0[j], r1 = rr1[j];
    float h0 = fmaxf(fmaf(r1, wt1[0], fmaf(r0, wt0[0], xv[it][0])), 0.f);
    float h1 = fmaxf(fmaf(r1, wt1[1], fmaf(r0, wt0[1], xv[it][1])), 0.f);
    float h2 = fmaxf(fmaf(r1, wt1[2], fmaf(r0, wt0[2], xv[it][2])), 0.f);
    float h3 = fmaxf(fmaf(r1, wt1[3], fmaf(r0, wt0[3], xv[it][3])), 0.f);
    int d = __builtin_amdgcn_cvt_pk_fp8_f32(h0, h1, 0, false);
    d     = __builtin_amdgcn_cvt_pk_fp8_f32(h2, h3, d, true);
    *reinterpret_cast<int*>(lA8 + j * LDA8 + c0) = d;
  }
  __syncthreads();

  unsigned long a[4], an[4];
#pragma unroll
  for(int mt = 0; mt < 4; ++mt)
    a[mt] = *reinterpret_cast<const unsigned long*>(lA8 + (mt * 16 + ln) * LDA8 + ph * 32 + quad * 8);
  f4v acc[4][4];
#pragma unroll
  for(int mt = 0; mt < 4; ++mt)
#pragma unroll
    for(int nt = 0; nt < 4; ++nt){
      acc[mt][nt][0]=0.f; acc[mt][nt][1]=0.f; acc[mt][nt][2]=0.f; acc[mt][nt][3]=0.f;
    }

#pragma unroll 2
  for(int s = 0; s < 16; ++s){
    const int sc = s & 1;
    const int p2 = (s + 2 + ph) & 15;                // B prefetch, depth 2
    const int p1 = (s + 1 + ph) & 15;                // A prefetch, depth 1
    ul2 nb0 = Bv[p2 * 1024 + off];
    ul2 nb1 = Bv[p2 * 1024 + off + 1];
#pragma unroll
    for(int mt = 0; mt < 4; ++mt)
      an[mt] = *reinterpret_cast<const unsigned long*>(lA8 + (mt * 16 + ln) * LDA8 + p1 * 32 + quad * 8);
    long bf0 = (long)bA[sc].x, bf1 = (long)bA[sc].y;
    long bf2 = (long)bB[sc].x, bf3 = (long)bB[sc].y;
#pragma unroll
    for(int mt = 0; mt < 4; ++mt){
      acc[mt][0] = __builtin_amdgcn_mfma_f32_16x16x32_fp8_fp8((long)a[mt], bf0, acc[mt][0], 0, 0, 0);
      acc[mt][1] = __builtin_amdgcn_mfma_f32_16x16x32_fp8_fp8((long)a[mt], bf1, acc[mt][1], 0, 0, 0);
      acc[mt][2] = __builtin_amdgcn_mfma_f32_16x16x32_fp8_fp8((long)a[mt], bf2, acc[mt][2], 0, 0, 0);
      acc[mt][3] = __builtin_amdgcn_mfma_f32_16x16x32_fp8_fp8((long)a[mt], bf3, acc[mt][3], 0, 0, 0);
    }
#pragma unroll
    for(int mt = 0; mt < 4; ++mt) a[mt] = an[mt];
    bA[sc] = nb0; bB[sc] = nb1;
  }

  // values (bf16, pre-scaled by log2e), fragment order: 8 coalesced 16B loads
  uint4 vv[8];
#pragma unroll
  for(int eb = 0; eb < 8; ++eb)
    vv[eb] = *reinterpret_cast<const uint4*>(vfrag + ((size_t)((b * 8 + w) * 8 + eb) * 64 + lane) * 8);

  // sigmoid (with 1/4096 unscale) + mask, fused with out1 rowsum
  float bb[4];
#pragma unroll
  for(int nt = 0; nt < 4; ++nt) bb[nt] = bimp[w * 64 + nt * 16 + ln];
#pragma unroll
  for(int mt = 0; mt < 4; ++mt)
#pragma unroll
    for(int r = 0; r < 4; ++r){
      float mk = msk[mt * 16 + quad * 4 + r];
      float p = 0.f;
#pragma unroll
      for(int nt = 0; nt < 4; ++nt){
        float z = fmaf(acc[mt][nt][r], ZSC, bb[nt]);
        float im = mk * __builtin_amdgcn_rcpf(1.f + __builtin_amdgcn_exp2f(z * -LOG2E));
        acc[mt][nt][r] = im;
        p += im;
      }
      p += __shfl_xor(p, 1, 64);
      p += __shfl_xor(p, 2, 64);
      p += __shfl_xor(p, 4, 64);
      p += __shfl_xor(p, 8, 64);
      if(ln == 0) atomicAdd(&rsum[mt * 16 + quad * 4 + r], p);
    }
  __syncthreads();
  if(tid < Tn) out1[(b * Tn + i) * Tn + tid] = rsum[tid] * (1.f / 512.f);

  // logsumexp over j: se = sum exp2(vl * imp), vl = values*log2e
  const unsigned int* vw = reinterpret_cast<const unsigned int*>(vv);
#pragma unroll
  for(int nt = 0; nt < 4; ++nt){
    float se = 0.f;
#pragma unroll
    for(int mt = 0; mt < 4; ++mt)
#pragma unroll
      for(int r = 0; r < 4; ++r){
        int e = mt * 16 + nt * 4 + r;
        unsigned int d = vw[e >> 1];
        float vl = bits2f((e & 1) ? (d & 0xffff0000u) : (d << 16));
        se += __builtin_amdgcn_exp2f(vl * acc[mt][nt][r]);
      }
    se += __shfl_xor(se, 16, 64);
    se += __shfl_xor(se, 32, 64);
    if(quad == 0){
      int idx = (b * Tn + i) * Cn + (w * 64 + nt * 16 + ln);
      out0[idx] = x[idx] + __builtin_amdgcn_logf(se) * LN2;
    }
  }
}

extern "C" void kernel_launch(void* const* d_in, const int* in_sizes, int n_in,
                              void* d_out, int out_size, void* d_ws, size_t ws_size,
                              hipStream_t stream){
  const float* x    = (const float*)d_in[0];
  const float* ts   = (const float*)d_in[1];
  const float* am   = (const float*)d_in[2];
  const float* Wp   = (const float*)d_in[3];
  const float* bp   = (const float*)d_in[4];
  const float* Wx   = (const float*)d_in[5];
  const float* bx   = (const float*)d_in[6];
  const float* Wt   = (const float*)d_in[7];
  const float* bt   = (const float*)d_in[8];
  const float* Wi   = (const float*)d_in[9];
  const float* bimp = (const float*)d_in[10];
  float* out0 = (float*)d_out;
  float* out1 = out0 + Bn * Tn * Cn;

  char* ws = (char*)d_ws;
  unsigned char*  Wsw8  = (unsigned char*)ws;                   // 256KB: Wi fp8 frags
  float*          xe    = (float*)(ws + 262144);                // 2MB f32 (scaled x16)
  unsigned short* vfrag = (unsigned short*)(ws + 2359296);      // 1MB bf16 frag-order
  float*          R     = (float*)(ws + 3407872);               // 512KB log1p table

  pre<<<448, 256, 0, stream>>>(x, ts, Wp, bp, Wx, bx, bt, Wi, xe, vfrag, Wsw8, R);
  fused<<<1024, 512, 0, stream>>>(x, am, Wt, bimp, Wsw8, R, xe, vfrag, out0, out1);
}